// Round 1
// baseline (128.997 us; speedup 1.0000x reference)
//
#include <hip/hip_runtime.h>

#define D 128
#define LAT 3
#define SD 22

// ---------------------------------------------------------------------------
// Kernel 1: fold the two linear chains into fused affine maps, stored in ws:
//   ws[0..383]    : J_enc [3][128]  = We3@We2@We1
//   ws[384..386]  : b_enc [3]       = We3@(We2@be1 + be2) + be3
//   ws[512..1023] : J_dec4 [128][4] = (J_dec[o][0..2], b_dec[o])
//                   J_dec = Wd3@Wd2@Wd1, b_dec = Wd3@(Wd2@bd1 + bd2) + bd3
// One block, 256 threads. Rewrites every used slot each call (deterministic).
// ---------------------------------------------------------------------------
__global__ __launch_bounds__(256) void fuse_weights(
    const float* __restrict__ We1, const float* __restrict__ be1,
    const float* __restrict__ We2, const float* __restrict__ be2,
    const float* __restrict__ We3, const float* __restrict__ be3,
    const float* __restrict__ Wd1, const float* __restrict__ bd1,
    const float* __restrict__ Wd2, const float* __restrict__ bd2,
    const float* __restrict__ Wd3, const float* __restrict__ bd3,
    float* __restrict__ ws)
{
    __shared__ float A1[3][64];   // We3@We2
    __shared__ float B1[64][3];   // Wd2@Wd1
    __shared__ float t2d[64];     // Wd2@bd1 + bd2
    const int t = threadIdx.x;

    if (t < 192) {
        {   // A1[r][c], r<3, c<64: dot over 32
            int r = t >> 6, c = t & 63;
            float s = 0.f;
            #pragma unroll 8
            for (int i = 0; i < 32; ++i) s += We3[r * 32 + i] * We2[i * 64 + c];
            A1[r][c] = s;
        }
        {   // B1[o][l], o<64, l<3: dot over 32
            int o = t / 3, l = t - o * 3;
            float s = 0.f;
            #pragma unroll 8
            for (int i = 0; i < 32; ++i) s += Wd2[o * 32 + i] * Wd1[i * 3 + l];
            B1[o][l] = s;
        }
    } else {
        int i = t - 192;  // 0..63
        float s = bd2[i];
        #pragma unroll 8
        for (int j = 0; j < 32; ++j) s += Wd2[i * 32 + j] * bd1[j];
        t2d[i] = s;
    }
    __syncthreads();

    // J_enc [3][128]: dot over 64
    for (int e = t; e < 3 * D; e += 256) {
        int r = e >> 7, c = e & 127;
        float s = 0.f;
        #pragma unroll 8
        for (int j = 0; j < 64; ++j) s += A1[r][j] * We1[j * D + c];
        ws[e] = s;
    }
    // b_enc [3]
    if (t < 3) {
        float s = be3[t];
        #pragma unroll 8
        for (int j = 0; j < 64; ++j) s += A1[t][j] * be1[j];
        #pragma unroll 8
        for (int i = 0; i < 32; ++i) s += We3[t * 32 + i] * be2[i];
        ws[384 + t] = s;
    }
    // J_dec4 [128][4]
    if (t < 128) {
        float s0 = 0.f, s1 = 0.f, s2 = 0.f, sb = bd3[t];
        #pragma unroll 8
        for (int j = 0; j < 64; ++j) {
            float w = Wd3[t * 64 + j];
            s0 += w * B1[j][0];
            s1 += w * B1[j][1];
            s2 += w * B1[j][2];
            sb += w * t2d[j];
        }
        ((float4*)(ws + 512))[t] = make_float4(s0, s1, s2, sb);
    }
}

// ---------------------------------------------------------------------------
// Kernel 2: one half-wave (32 lanes) per row. float4 loads/stores; 5-step
// shuffle butterfly for the six length-128 dot products; SINDy library +
// dzb computed redundantly per lane (EW hoisted to registers).
// Output layout (flat, in return order):
//   z   @ 0      [N,3]
//   dz  @ 3N     [N,3]
//   dzb @ 6N     [N,3]
//   xb  @ 9N     [N,128]
//   dxb @ 137N   [N,128]
// ---------------------------------------------------------------------------
__global__ __launch_bounds__(256) void sindy_fused(
    const float* __restrict__ x, const float* __restrict__ dx,
    const float* __restrict__ EW, const float* __restrict__ Eb,
    const float* __restrict__ ws, float* __restrict__ out, int nrows)
{
    const int lane = threadIdx.x & 31;   // lane within half-wave
    const int half = threadIdx.x >> 5;   // 0..7 within block

    // Hoisted fused weights (L1/L2-broadcast reads, once per thread)
    const float4 je0 = *(const float4*)(ws + 0 * D + lane * 4);
    const float4 je1 = *(const float4*)(ws + 1 * D + lane * 4);
    const float4 je2 = *(const float4*)(ws + 2 * D + lane * 4);
    const float benc0 = ws[384], benc1 = ws[385], benc2 = ws[386];
    const float4 jd0 = ((const float4*)(ws + 512))[lane * 4 + 0];
    const float4 jd1 = ((const float4*)(ws + 512))[lane * 4 + 1];
    const float4 jd2 = ((const float4*)(ws + 512))[lane * 4 + 2];
    const float4 jd3 = ((const float4*)(ws + 512))[lane * 4 + 3];

    float ew[LAT][SD];
    #pragma unroll
    for (int r = 0; r < LAT; ++r)
        #pragma unroll
        for (int k = 0; k < SD; ++k) ew[r][k] = EW[r * SD + k];
    const float eb0 = Eb[0], eb1 = Eb[1], eb2 = Eb[2];

    const int xbBase  = 9 * nrows;
    const int dxbBase = 137 * nrows;
    const int rowsPerGrid = gridDim.x * 8;

    for (int row = blockIdx.x * 8 + half; row < nrows; row += rowsPerGrid) {
        const float4 xv  = *(const float4*)(x  + row * D + lane * 4);
        const float4 dxv = *(const float4*)(dx + row * D + lane * 4);

        float pz0 = je0.x * xv.x + je0.y * xv.y + je0.z * xv.z + je0.w * xv.w;
        float pz1 = je1.x * xv.x + je1.y * xv.y + je1.z * xv.z + je1.w * xv.w;
        float pz2 = je2.x * xv.x + je2.y * xv.y + je2.z * xv.z + je2.w * xv.w;
        float pd0 = je0.x * dxv.x + je0.y * dxv.y + je0.z * dxv.z + je0.w * dxv.w;
        float pd1 = je1.x * dxv.x + je1.y * dxv.y + je1.z * dxv.z + je1.w * dxv.w;
        float pd2 = je2.x * dxv.x + je2.y * dxv.y + je2.z * dxv.z + je2.w * dxv.w;

        // butterfly reduce within the 32-lane half (masks < 32 stay in-half)
        #pragma unroll
        for (int m = 16; m >= 1; m >>= 1) {
            pz0 += __shfl_xor(pz0, m);
            pz1 += __shfl_xor(pz1, m);
            pz2 += __shfl_xor(pz2, m);
            pd0 += __shfl_xor(pd0, m);
            pd1 += __shfl_xor(pd1, m);
            pd2 += __shfl_xor(pd2, m);
        }

        const float z0 = pz0 + benc0, z1 = pz1 + benc1, z2 = pz2 + benc2;

        // SINDy library (torch loop order): 3 ones, 3 linear, 6 quad, 10 cubic
        const float q00 = z0 * z0, q01 = z0 * z1, q02 = z0 * z2;
        const float q11 = z1 * z1, q12 = z1 * z2, q22 = z2 * z2;
        float th[SD];
        th[0] = 1.f;  th[1] = 1.f;  th[2] = 1.f;
        th[3] = z0;   th[4] = z1;   th[5] = z2;
        th[6] = q00;  th[7] = q01;  th[8] = q02;
        th[9] = q11;  th[10] = q12; th[11] = q22;
        th[12] = q00 * z0; th[13] = q00 * z1; th[14] = q00 * z2;
        th[15] = q11 * z0; th[16] = q12 * z0; th[17] = q22 * z0;
        th[18] = q11 * z1; th[19] = q11 * z2; th[20] = q22 * z1;
        th[21] = q22 * z2;

        float dzb0 = eb0, dzb1 = eb1, dzb2 = eb2;
        #pragma unroll
        for (int k = 0; k < SD; ++k) {
            dzb0 += ew[0][k] * th[k];
            dzb1 += ew[1][k] * th[k];
            dzb2 += ew[2][k] * th[k];
        }

        // small outputs: z, dz, dzb (3 floats each per row)
        const int n3 = row * 3;
        if (lane < 3) {
            const float zv = (lane == 0) ? z0 : (lane == 1) ? z1 : z2;
            const float dv = (lane == 0) ? pd0 : (lane == 1) ? pd1 : pd2;
            const float bv = (lane == 0) ? dzb0 : (lane == 1) ? dzb1 : dzb2;
            out[n3 + lane] = zv;
            out[3 * nrows + n3 + lane] = dv;
            out[6 * nrows + n3 + lane] = bv;
        }

        // xb (with decoder bias) and dxb (no bias), coalesced float4
        float4 xbv, dxbv;
        xbv.x = jd0.x * z0 + jd0.y * z1 + jd0.z * z2 + jd0.w;
        xbv.y = jd1.x * z0 + jd1.y * z1 + jd1.z * z2 + jd1.w;
        xbv.z = jd2.x * z0 + jd2.y * z1 + jd2.z * z2 + jd2.w;
        xbv.w = jd3.x * z0 + jd3.y * z1 + jd3.z * z2 + jd3.w;
        dxbv.x = jd0.x * dzb0 + jd0.y * dzb1 + jd0.z * dzb2;
        dxbv.y = jd1.x * dzb0 + jd1.y * dzb1 + jd1.z * dzb2;
        dxbv.z = jd2.x * dzb0 + jd2.y * dzb1 + jd2.z * dzb2;
        dxbv.w = jd3.x * dzb0 + jd3.y * dzb1 + jd3.z * dzb2;

        *(float4*)(out + xbBase  + row * D + lane * 4) = xbv;
        *(float4*)(out + dxbBase + row * D + lane * 4) = dxbv;
    }
}

extern "C" void kernel_launch(void* const* d_in, const int* in_sizes, int n_in,
                              void* d_out, int out_size, void* d_ws, size_t ws_size,
                              hipStream_t stream) {
    const float* x   = (const float*)d_in[0];
    const float* dx  = (const float*)d_in[1];
    const float* We1 = (const float*)d_in[2];
    const float* be1 = (const float*)d_in[3];
    const float* We2 = (const float*)d_in[4];
    const float* be2 = (const float*)d_in[5];
    const float* We3 = (const float*)d_in[6];
    const float* be3 = (const float*)d_in[7];
    const float* Wd1 = (const float*)d_in[8];
    const float* bd1 = (const float*)d_in[9];
    const float* Wd2 = (const float*)d_in[10];
    const float* bd2 = (const float*)d_in[11];
    const float* Wd3 = (const float*)d_in[12];
    const float* bd3 = (const float*)d_in[13];
    const float* EW  = (const float*)d_in[14];
    const float* Eb  = (const float*)d_in[15];

    float* ws  = (float*)d_ws;
    float* out = (float*)d_out;
    const int nrows = in_sizes[0] / D;   // 262144

    fuse_weights<<<1, 256, 0, stream>>>(We1, be1, We2, be2, We3, be3,
                                        Wd1, bd1, Wd2, bd2, Wd3, bd3, ws);

    // memory-bound: 2048 resident-capable blocks, grid-stride over rows
    sindy_fused<<<2048, 256, 0, stream>>>(x, dx, EW, Eb, ws, out, nrows);
}